// Round 1
// 396.341 us; speedup vs baseline: 1.0672x; 1.0672x over previous
//
#include <hip/hip_runtime.h>
#include <math.h>

#define NPTS   32768
#define NK     4
#define GRIDN  16
#define CIN    64
#define COUT   64
#define NCELLS (NK*GRIDN*GRIDN*GRIDN)   /* 16384 */
#define CAP    128                      /* bucket capacity; mean fill = 16 */

typedef __attribute__((ext_vector_type(8))) short  short8;
typedef __attribute__((ext_vector_type(4))) float  f32x4;

static __device__ inline unsigned short f2bf(float f) {
    unsigned int u = __builtin_bit_cast(unsigned int, f);
    unsigned int r = u + 0x7fff + ((u >> 16) & 1);   // RNE truncate to bf16
    return (unsigned short)(r >> 16);
}

// ---------------------------------------------------------------------------
// Pass 1 (single point pass): scatter (pid, weight) entries directly into
// fixed-capacity per-cell buckets. One thread per (point, corner). Bucket
// order is irrelevant; CAP=128 >> Poisson(16) tail even for clipped corner
// cells, so overflow drop is a never-taken safety valve.
// ---------------------------------------------------------------------------
__global__ void k_scatter(const int* __restrict__ pidx, const float* __restrict__ pos,
                          int* __restrict__ cnt, int2* __restrict__ ent,
                          int n, int cap) {
    int t = blockIdx.x * blockDim.x + threadIdx.x;
    int p = t >> 3;
    if (p >= n) return;
    int c  = t & 7;
    int pk = pidx[p];
    float lx = pos[3*p+0]*16.f - 0.5f;
    float ly = pos[3*p+1]*16.f - 0.5f;
    float lz = pos[3*p+2]*16.f - 0.5f;
    float flx = floorf(lx), fly = floorf(ly), flz = floorf(lz);
    float tx = lx - flx, ty = ly - fly, tz = lz - flz;
    int fx = (int)flx, fy = (int)fly, fz = (int)flz;
    int c0 = c & 1, c1 = (c >> 1) & 1, c2 = (c >> 2) & 1;
    int ix = min(max(fx + c0, 0), GRIDN-1);
    int iy = min(max(fy + c1, 0), GRIDN-1);
    int iz = min(max(fz + c2, 0), GRIDN-1);
    float w = (c0 ? tx : 1.f - tx) * (c1 ? ty : 1.f - ty) * (c2 ? tz : 1.f - tz);
    int cell = ((pk*GRIDN + iz)*GRIDN + iy)*GRIDN + ix;
    int e = atomicAdd(&cnt[cell], 1);
    if (e < cap) ent[(size_t)cell * cap + e] = make_int2(p, __float_as_int(w));
}

// ---------------------------------------------------------------------------
// Pass 2: ONE WAVE PER CELL. No LDS, no __syncthreads — fully autonomous.
// The wave loads B-fragments for all 4 cout-chunks straight from global
// (64 dword loads; lanes m=0..15 hit consecutive dwords -> 64B segments;
// total 16 KB per cell, each element exactly once), converts to bf16 in
// registers, then streams entries in 16-row batches with 8 MFMAs each.
// Entry pid/weight for the epilogue rows comes via __shfl, not LDS.
//
// Fragment layouts (gfx950, verified by the passing predecessor kernel):
//   A[m][k]: m = lane&15, k = (lane>>4)*8 + j
//   B[k][n]: n = lane&15, k = (lane>>4)*8 + j
//   D[m][n]: n = lane&15, m = (lane>>4)*4 + reg
// ---------------------------------------------------------------------------
__global__ __launch_bounds__(256)
void k_main(const float* __restrict__ xs, const float* __restrict__ kernels,
            const float* __restrict__ biases, const int* __restrict__ cnt,
            const int2* __restrict__ ent, float* __restrict__ out, int cap) {
    int tid  = threadIdx.x;
    int wv   = tid >> 6;
    int l    = tid & 63;
    int q    = l >> 4;        // k-chunk / D row-quad
    int m    = l & 15;        // A-row / B-col / D-col
    int cell = blockIdx.x * 4 + wv;

    int count = min(cnt[cell], cap);
    if (count == 0) return;

    // ---- B fragments for all 4 cout-chunks, direct from global ----
    const float* Kg = kernels + (size_t)cell * (CIN * COUT);
    short8 Bf[4][2];
#pragma unroll
    for (int c = 0; c < 4; ++c)
#pragma unroll
        for (int s = 0; s < 2; ++s)
#pragma unroll
            for (int j = 0; j < 8; ++j)
                Bf[c][s][j] = (short)f2bf(Kg[(s*32 + q*8 + j)*COUT + c*16 + m]);

    float bias_c[4];
#pragma unroll
    for (int c = 0; c < 4; ++c)
        bias_c[c] = biases[(size_t)cell * COUT + c*16 + m];

    const int2* eb = ent + (size_t)cell * cap;
    int nb = (count + 15) >> 4;
    for (int b = 0; b < nb; ++b) {
        int r0 = b << 4;
        int2 em = (r0 + m < count) ? eb[r0 + m] : make_int2(0, 0);
        int apid = em.x;      // pad rows read row 0 (finite), w=0 skips epilogue

        // ---- A fragments: 8 consecutive floats per lane per k-half ----
        short8 af[2];
#pragma unroll
        for (int s = 0; s < 2; ++s) {
            const float4 x0 = *(const float4*)&xs[(size_t)apid*CIN + s*32 + q*8 + 0];
            const float4 x1 = *(const float4*)&xs[(size_t)apid*CIN + s*32 + q*8 + 4];
            af[s][0] = (short)f2bf(x0.x); af[s][1] = (short)f2bf(x0.y);
            af[s][2] = (short)f2bf(x0.z); af[s][3] = (short)f2bf(x0.w);
            af[s][4] = (short)f2bf(x1.x); af[s][5] = (short)f2bf(x1.y);
            af[s][6] = (short)f2bf(x1.z); af[s][7] = (short)f2bf(x1.w);
        }

        f32x4 acc[4];
#pragma unroll
        for (int c = 0; c < 4; ++c) acc[c] = (f32x4){0.f, 0.f, 0.f, 0.f};
#pragma unroll
        for (int s = 0; s < 2; ++s)
#pragma unroll
            for (int c = 0; c < 4; ++c)
                acc[c] = __builtin_amdgcn_mfma_f32_16x16x32_bf16(af[s], Bf[c][s], acc[c], 0, 0, 0);

        // ---- epilogue: D row r = q*4+reg lives on lanes (r<16) -> shfl ----
#pragma unroll
        for (int reg = 0; reg < 4; ++reg) {
            int   r     = q*4 + reg;
            int   pid_r = __shfl(em.x, r);
            float w_r   = __shfl(__int_as_float(em.y), r);
            if (w_r != 0.f) {
                float* orow = out + (size_t)pid_r * COUT + m;
#pragma unroll
                for (int c = 0; c < 4; ++c)
                    unsafeAtomicAdd(&orow[c*16], w_r * (acc[c][reg] + bias_c[c]));
            }
        }
    }
}

// ---------------------------------------------------------------------------
extern "C" void kernel_launch(void* const* d_in, const int* in_sizes, int n_in,
                              void* d_out, int out_size, void* d_ws, size_t ws_size,
                              hipStream_t stream) {
    const int*   pidx    = (const int*)  d_in[0];
    const float* pos     = (const float*)d_in[1];
    const float* xs      = (const float*)d_in[2];
    const float* kernels = (const float*)d_in[3];
    const float* biases  = (const float*)d_in[4];
    float*       out     = (float*)d_out;
    int n = in_sizes[0];   // 32768

    // ws layout: cnt[NCELLS] ints | ent[NCELLS*CAP] int2 (8B aligned at 64KB)
    int*  cnt = (int*)d_ws;
    int2* ent = (int2*)((char*)d_ws + (size_t)NCELLS * sizeof(int));

    // runtime clamp so we never write outside the provided workspace
    int cap = CAP;
    size_t avail = (ws_size > (size_t)NCELLS * sizeof(int))
                 ? (ws_size - (size_t)NCELLS * sizeof(int)) / (sizeof(int2) * NCELLS)
                 : 0;
    if ((size_t)cap > avail) cap = (int)avail;

    hipMemsetAsync(cnt, 0, NCELLS * sizeof(int), stream);
    hipMemsetAsync(d_out, 0, (size_t)out_size * sizeof(float), stream);

    int eblocks = (n * 8 + 255) / 256;
    k_scatter<<<eblocks, 256, 0, stream>>>(pidx, pos, cnt, ent, n, cap);
    k_main  <<<NCELLS/4, 256, 0, stream>>>(xs, kernels, biases, cnt, ent, out, cap);
}